// Round 18
// baseline (120.580 us; speedup 1.0000x reference)
//
#include <hip/hip_runtime.h>

#define N_TOK 4096
#define C_DIM 512
#define CI_DIM 128
#define B_DIM 4
#define KVSPLIT 4
#define KVBLK 32
#define NIT (N_TOK / KVSPLIT / KVBLK)
#define LOG2E 1.4426950408889634f
#define RESCALE_THR2 11.541560327111708f   /* 8 * log2(e), base-2 units */

typedef unsigned short u16;
typedef unsigned int u32;
typedef unsigned long long u64;
typedef __attribute__((ext_vector_type(8))) short bf16x8;
typedef __attribute__((ext_vector_type(4))) float f32x4;
typedef __attribute__((ext_vector_type(8))) unsigned short u16x8;
typedef __attribute__((ext_vector_type(4))) float float4v;

// alias-safe views of LDS tiles (stored via one type, read via another)
typedef unsigned long long __attribute__((may_alias)) u64a;
typedef bf16x8 __attribute__((may_alias)) bf16x8a;
typedef u16x8 __attribute__((may_alias)) u16x8a;

__device__ __forceinline__ u16 f2bf(float f) {
    union { float f; u32 u; } v; v.f = f;
    u32 r = (v.u + 0x7fffu + ((v.u >> 16) & 1u)) >> 16;
    return (u16)r;
}
__device__ __forceinline__ float bf2f(u16 h) {
    union { u32 u; float f; } v; v.u = (u32)h << 16;
    return v.f;
}
__device__ __forceinline__ u32 cvt_pk_bf16(float a, float b) {
    u32 r;
    asm("v_cvt_pk_bf16_f32 %0, %1, %2" : "=v"(r) : "v"(a), "v"(b));
    return r;
}
// 2^x via the native transcendental (v_exp_f32 computes exp2)
__device__ __forceinline__ float exp2_fast(float a) {
    float r;
    asm("v_exp_f32 %0, %1" : "=v"(r) : "v"(a));
    return r;
}

// ---------------------------------------------------------------------------
// Prepass 1: transpose+convert x f32 [B][C][N] -> xT bf16 [B][N][C]
// ---------------------------------------------------------------------------
__global__ __launch_bounds__(256) void xpose_kernel(
    const float* __restrict__ x, u16* __restrict__ xT)
{
    const int n0 = blockIdx.x * 64;
    const int c0 = blockIdx.y * 64;
    const int b  = blockIdx.z;
    __shared__ u16 Ts[64][72];
    const int t = threadIdx.x;

    const float* xb = x + (size_t)b * C_DIM * N_TOK;
    for (int idx = t; idx < 4096; idx += 256) {
        int c = idx >> 6, n = idx & 63;
        Ts[n][c] = f2bf(xb[(size_t)(c0 + c) * N_TOK + n0 + n]);
    }
    __syncthreads();
    u16* xTb = xT + (size_t)b * N_TOK * C_DIM;
    for (int idx = t; idx < 512; idx += 256) {
        int n = idx >> 3, c8 = idx & 7;
        *(u16x8*)&xTb[(size_t)(n0 + n) * C_DIM + c0 + c8 * 8] =
            *(u16x8*)&Ts[n][c8 * 8];
    }
}

// ---------------------------------------------------------------------------
// Prepass 2: convert weights to bf16 (layouts unchanged).
// ---------------------------------------------------------------------------
__global__ __launch_bounds__(256) void wconv_kernel(
    const float* __restrict__ wq, const float* __restrict__ wk,
    const float* __restrict__ wv, const float* __restrict__ wo,
    u16* __restrict__ wqB, u16* __restrict__ wkB,
    u16* __restrict__ wvB, u16* __restrict__ woB)
{
    const int z = blockIdx.y;
    const float* src = (z == 0) ? wq : (z == 1) ? wk : (z == 2) ? wv : wo;
    u16* dst = (z == 0) ? wqB : (z == 1) ? wkB : (z == 2) ? wvB : woB;
    const int i0 = (blockIdx.x * 256 + threadIdx.x) * 8;
    float4v a = *(const float4v*)&src[i0];
    float4v b = *(const float4v*)&src[i0 + 4];
    u16x8 o;
    o[0] = f2bf(a[0]); o[1] = f2bf(a[1]); o[2] = f2bf(a[2]); o[3] = f2bf(a[3]);
    o[4] = f2bf(b[0]); o[5] = f2bf(b[1]); o[6] = f2bf(b[2]); o[7] = f2bf(b[3]);
    *(u16x8*)&dst[i0] = o;
}

// ---------------------------------------------------------------------------
// Kernel A: q/k/v projections via MFMA, LDS-staged operand tiles. (r12,
// verified). q output (z==0) is pre-scaled by log2(e) so attention's
// softmax can use bare v_exp (exp2) with no per-element multiply.
// ---------------------------------------------------------------------------
__global__ __launch_bounds__(256) void qkv_gemm_kernel(
    const u16* __restrict__ xT,
    const u16* __restrict__ wqB, const u16* __restrict__ wkB,
    const u16* __restrict__ wvB,
    const float* __restrict__ bq, const float* __restrict__ bk,
    const float* __restrict__ bv,
    u16* __restrict__ qT, u16* __restrict__ kT, u16* __restrict__ vB)
{
    const int n0 = blockIdx.x * 128;
    const int b  = blockIdx.y;
    const int z  = blockIdx.z;
    const u16* wz = (z == 0) ? wqB : (z == 1) ? wkB : wvB;
    const float* bias = (z == 0) ? bq : (z == 1) ? bk : bv;

    __shared__ u16 Xs[128][72];
    __shared__ u16 Ws[128][72];

    const int t  = threadIdx.x;
    const int w  = t >> 6;
    const int l  = t & 63;
    const int lg = l >> 4;
    const int li = l & 15;
    const int cb = w * 32;

    const u16* xTb = xT + (size_t)b * N_TOK * C_DIM;

    const int srow = t >> 1;
    const int sh   = (t & 1) * 32;

    f32x4 acc[8][2];
#pragma unroll
    for (int m = 0; m < 8; ++m)
#pragma unroll
        for (int j = 0; j < 2; ++j)
#pragma unroll
            for (int r = 0; r < 4; ++r) acc[m][j][r] = 0.f;

    u16x8 xv[4], wv[4];
#pragma unroll
    for (int g = 0; g < 4; ++g) {
        xv[g] = *(const u16x8a*)&xTb[(size_t)(n0 + srow) * C_DIM + sh + g * 8];
        wv[g] = *(const u16x8a*)&wz[(size_t)srow * C_DIM + sh + g * 8];
    }

    const u16 (*A_lds)[72] = (z < 2) ? Xs : Ws;
    const u16 (*B_lds)[72] = (z < 2) ? Ws : Xs;

#pragma unroll 1
    for (int kk = 0; kk < C_DIM / 64; ++kk) {
        __syncthreads();
#pragma unroll
        for (int g = 0; g < 4; ++g) {
            *(u16x8a*)&Xs[srow][sh + g * 8] = xv[g];
            *(u16x8a*)&Ws[srow][sh + g * 8] = wv[g];
        }
        __syncthreads();

        if (kk + 1 < C_DIM / 64) {
            const int k0 = (kk + 1) * 64;
#pragma unroll
            for (int g = 0; g < 4; ++g) {
                xv[g] = *(const u16x8a*)&xTb[(size_t)(n0 + srow) * C_DIM + k0 + sh + g * 8];
                wv[g] = *(const u16x8a*)&wz[(size_t)srow * C_DIM + k0 + sh + g * 8];
            }
        }

#pragma unroll
        for (int kc = 0; kc < 2; ++kc) {
            bf16x8 af[8], bfv[2];
#pragma unroll
            for (int m = 0; m < 8; ++m)
                af[m] = *(const bf16x8a*)&A_lds[m * 16 + li][kc * 32 + lg * 8];
#pragma unroll
            for (int j = 0; j < 2; ++j)
                bfv[j] = *(const bf16x8a*)&B_lds[cb + j * 16 + li][kc * 32 + lg * 8];
            __builtin_amdgcn_s_setprio(1);
#pragma unroll
            for (int m = 0; m < 8; ++m)
#pragma unroll
                for (int j = 0; j < 2; ++j)
                    acc[m][j] = __builtin_amdgcn_mfma_f32_16x16x32_bf16(
                        af[m], bfv[j], acc[m][j], 0, 0, 0);
            __builtin_amdgcn_s_setprio(0);
        }
    }

    if (z < 2) {
        u16* dst = ((z == 0) ? qT : kT) + (size_t)b * N_TOK * CI_DIM;
        const float osc = (z == 0) ? LOG2E : 1.0f;   // pre-scale q by log2(e)
#pragma unroll
        for (int j = 0; j < 2; ++j) {
            float bia = bias[cb + j * 16 + li];
#pragma unroll
            for (int m = 0; m < 8; ++m)
#pragma unroll
                for (int r = 0; r < 4; ++r)
                    dst[(size_t)(n0 + m * 16 + lg * 4 + r) * CI_DIM + cb + j * 16 + li] =
                        f2bf((acc[m][j][r] + bia) * osc);
        }
    } else {
        u16* dst = vB + (size_t)b * CI_DIM * N_TOK;
#pragma unroll
        for (int m = 0; m < 8; ++m)
#pragma unroll
            for (int r = 0; r < 4; ++r) {
                int o = m * 16 + lg * 4 + r;
                float bia = bias[o];
#pragma unroll
                for (int j = 0; j < 2; ++j)
                    dst[(size_t)o * N_TOK + n0 + cb + j * 16 + li] =
                        f2bf(acc[m][j][r] + bia);
            }
    }
}

// ---------------------------------------------------------------------------
// Kernel B: MFMA flash attention (r12 verified structure). Scores arrive
// pre-scaled by log2(e) (q-side fold) -> softmax uses bare v_exp (exp2),
// saving one v_mul per exponential. All max/l bookkeeping in base-2 units.
// grid = 512 blocks 1-D; x = combo + 16*qb; combo = b + 4*kvh (XCD swizzle).
// ---------------------------------------------------------------------------
__global__ __launch_bounds__(256) void attn_mfma_kernel(
    const u16* __restrict__ qT,   // [B][N][CI] (pre-scaled by log2e)
    const u16* __restrict__ kT,   // [B][N][CI]
    const u16* __restrict__ vB,   // [B][CI][N]
    u16* __restrict__ Opart,      // [4][B][N][CI] bf16, unnormalized
    float* __restrict__ Mout,     // [4][B][N] (base-2 units)
    float* __restrict__ Lout)     // [4][B][N]
{
    const int x   = blockIdx.x;
    const int qb  = x >> 4;         // [0,32)
    const int b   = x & 3;          // combo = x & 15 -> same XCD per combo
    const int kvh = (x >> 2) & 3;
    const int j_beg = kvh * (N_TOK / KVSPLIT);

    __shared__ u16 Ks[KVBLK][152];   // K tile, token-major (19-quad stride)
    __shared__ u16 Vs[CI_DIM][56];   // V tile, channel-major (7-quad stride)
    __shared__ u16 Ps[4][32][40];    // per-wave P tile (5-quad stride)

    const int t  = threadIdx.x;
    const int w  = t >> 6;
    const int l  = t & 63;
    const int lg = l >> 4;
    const int li = l & 15;
    const int qw = qb * 128 + w * 32;   // this wave's first query row

    // staging coordinates (coalesced global reads)
    const int krow = t >> 3, kc8 = t & 7;    // K: 32 rows x 8 chunks of 16 u16
    const int vch  = t >> 1, vh  = t & 1;    // V: 128 ch x 2 chunks of 16 u16

    const u16* qTb = qT + (size_t)b * N_TOK * CI_DIM;
    const u16* kTb = kT + (size_t)b * N_TOK * CI_DIM;
    const u16* vBb = vB + (size_t)b * CI_DIM * N_TOK;

    // Q fragments direct from global (once)
    bf16x8 qf[2][4];
#pragma unroll
    for (int qt = 0; qt < 2; ++qt)
#pragma unroll
        for (int kc = 0; kc < 4; ++kc)
            qf[qt][kc] = *(const bf16x8*)&qTb[(size_t)(qw + qt * 16 + li) * CI_DIM + kc * 32 + lg * 8];

    f32x4 Oacc[2][8];
#pragma unroll
    for (int qt = 0; qt < 2; ++qt)
#pragma unroll
        for (int ct = 0; ct < 8; ++ct)
#pragma unroll
            for (int r = 0; r < 4; ++r) Oacc[qt][ct][r] = 0.f;

    float mrun[2] = {-1e30f, -1e30f};
    float lrun[2] = {0.f, 0.f};     // per-lane partials

    // prologue: prefetch tile 0 into regs
    u16x8 kv0, kv1, vv0, vv1;
    {
        const u16* ksrc = &kTb[(size_t)(j_beg + krow) * CI_DIM + kc8 * 16];
        kv0 = *(const u16x8a*)&ksrc[0];
        kv1 = *(const u16x8a*)&ksrc[8];
        const u16* vsrc = &vBb[(size_t)vch * N_TOK + j_beg + vh * 16];
        vv0 = *(const u16x8a*)&vsrc[0];
        vv1 = *(const u16x8a*)&vsrc[8];
    }

#pragma unroll 1
    for (int it = 0; it < NIT; ++it) {
        // (A) all waves done reading previous tile
        __syncthreads();
        *(u16x8a*)&Ks[krow][kc8 * 16]     = kv0;
        *(u16x8a*)&Ks[krow][kc8 * 16 + 8] = kv1;
        *(u16x8a*)&Vs[vch][vh * 16]       = vv0;
        *(u16x8a*)&Vs[vch][vh * 16 + 8]   = vv1;
        // (B) tile ready
        __syncthreads();

        // prefetch next tile into regs; latency hides under compute below
        if (it + 1 < NIT) {
            const int jn = j_beg + (it + 1) * KVBLK;
            const u16* ksrc = &kTb[(size_t)(jn + krow) * CI_DIM + kc8 * 16];
            kv0 = *(const u16x8a*)&ksrc[0];
            kv1 = *(const u16x8a*)&ksrc[8];
            const u16* vsrc = &vBb[(size_t)vch * N_TOK + jn + vh * 16];
            vv0 = *(const u16x8a*)&vsrc[0];
            vv1 = *(const u16x8a*)&vsrc[8];
        }

        // ---- QK^T (swapped): S^T[j][i], fragments from LDS
        bf16x8 ak[2][4];
#pragma unroll
        for (int jt = 0; jt < 2; ++jt)
#pragma unroll
            for (int kc = 0; kc < 4; ++kc)
                ak[jt][kc] = *(const bf16x8a*)&Ks[jt * 16 + li][kc * 32 + lg * 8];

        f32x4 sacc[2][2];
#pragma unroll
        for (int qt = 0; qt < 2; ++qt)
#pragma unroll
            for (int jt = 0; jt < 2; ++jt)
#pragma unroll
                for (int r = 0; r < 4; ++r) sacc[qt][jt][r] = 0.f;
        __builtin_amdgcn_s_setprio(1);
#pragma unroll
        for (int jt = 0; jt < 2; ++jt)
#pragma unroll
            for (int kc = 0; kc < 4; ++kc) {
                sacc[0][jt] = __builtin_amdgcn_mfma_f32_16x16x32_bf16(ak[jt][kc], qf[0][kc], sacc[0][jt], 0, 0, 0);
                sacc[1][jt] = __builtin_amdgcn_mfma_f32_16x16x32_bf16(ak[jt][kc], qf[1][kc], sacc[1][jt], 0, 0, 0);
            }
        __builtin_amdgcn_s_setprio(0);

        // ---- softmax (base-2): shuffle-free common path (defer-max)
#pragma unroll
        for (int qt = 0; qt < 2; ++qt) {
            float tl = sacc[qt][0][0];
#pragma unroll
            for (int jt = 0; jt < 2; ++jt)
#pragma unroll
                for (int r = 0; r < 4; ++r) tl = fmaxf(tl, sacc[qt][jt][r]);

            if (__any(tl > mrun[qt] + RESCALE_THR2)) {
                float tmax = fmaxf(tl, __shfl_xor(tl, 16));
                tmax = fmaxf(tmax, __shfl_xor(tmax, 32));
                float mold = mrun[qt];
                float mnew = fmaxf(mold, tmax);
                float scale = exp2_fast(mold - mnew);
                lrun[qt] *= scale;
                mrun[qt] = mnew;
#pragma unroll
                for (int r = 0; r < 4; ++r) {
                    float sc_r = __shfl(scale, lg * 4 + r);
#pragma unroll
                    for (int ct = 0; ct < 8; ++ct) Oacc[qt][ct][r] *= sc_r;
                }
            }
            float m = mrun[qt];
            float psum = 0.f;
#pragma unroll
            for (int jt = 0; jt < 2; ++jt) {
                float p0 = exp2_fast(sacc[qt][jt][0] - m);
                float p1 = exp2_fast(sacc[qt][jt][1] - m);
                float p2 = exp2_fast(sacc[qt][jt][2] - m);
                float p3 = exp2_fast(sacc[qt][jt][3] - m);
                psum += (p0 + p1) + (p2 + p3);
                u32 lo = cvt_pk_bf16(p0, p1);
                u32 hi = cvt_pk_bf16(p2, p3);
                u64 pk = (u64)lo | ((u64)hi << 32);
                *(u64a*)&Ps[w][qt * 16 + li][jt * 16 + lg * 4] = pk;
            }
            lrun[qt] += psum;
        }

        // order P stores before PV reads
        asm volatile("" ::: "memory");

        // ---- PV: O^T[i][c] += P[i][j] * V^T[j][c]  (K=32, one slice)
        bf16x8 ap0 = *(const bf16x8a*)&Ps[w][li][lg * 8];
        bf16x8 ap1 = *(const bf16x8a*)&Ps[w][16 + li][lg * 8];
        __builtin_amdgcn_s_setprio(1);
#pragma unroll
        for (int ct = 0; ct < 8; ++ct) {
            bf16x8 bv = *(const bf16x8a*)&Vs[ct * 16 + li][lg * 8];
            Oacc[0][ct] = __builtin_amdgcn_mfma_f32_16x16x32_bf16(ap0, bv, Oacc[0][ct], 0, 0, 0);
            Oacc[1][ct] = __builtin_amdgcn_mfma_f32_16x16x32_bf16(ap1, bv, Oacc[1][ct], 0, 0, 0);
        }
        __builtin_amdgcn_s_setprio(0);
    }

    // ---- epilogue: finish l (cross-lane reduce), write m/l + bf16 O partial
#pragma unroll
    for (int qt = 0; qt < 2; ++qt) {
        lrun[qt] += __shfl_xor(lrun[qt], 16);
        lrun[qt] += __shfl_xor(lrun[qt], 32);
    }
    const size_t mlbase = ((size_t)kvh * B_DIM + b) * N_TOK + qw;
    if (lg == 0) {
#pragma unroll
        for (int qt = 0; qt < 2; ++qt) {
            Mout[mlbase + qt * 16 + li] = mrun[qt];
            Lout[mlbase + qt * 16 + li] = lrun[qt];
        }
    }
    u16* Ob = Opart + mlbase * CI_DIM;
#pragma unroll
    for (int qt = 0; qt < 2; ++qt)
#pragma unroll
        for (int ct = 0; ct < 8; ++ct)
#pragma unroll
            for (int r = 0; r < 4; ++r)
                Ob[(size_t)(qt * 16 + lg * 4 + r) * CI_DIM + ct * 16 + li] =
                    f2bf(Oacc[qt][ct][r]);
}

// ---------------------------------------------------------------------------
// Kernel C: merge the 4 KV-quarter partials -> attnoB bf16 [B][N][CI]
// (r12 structure; m-deltas are base-2 -> exp2_fast)
// ---------------------------------------------------------------------------
__global__ __launch_bounds__(256) void attn_merge_kernel(
    const u16* __restrict__ Opart, const float* __restrict__ Mout,
    const float* __restrict__ Lout, u16* __restrict__ attnoB)
{
    const int qb = blockIdx.x;
    const int b  = blockIdx.y;
    const int t  = threadIdx.x;
    const int i  = qb * 64 + (t & 63);
    const int c0 = (t >> 6) * 32;

    size_t ns[KVSPLIT];
    float cs[KVSPLIT];
    float m = -1e30f;
#pragma unroll
    for (int s = 0; s < KVSPLIT; ++s) {
        ns[s] = ((size_t)s * B_DIM + b) * N_TOK + i;
        cs[s] = Mout[ns[s]];
        m = fmaxf(m, cs[s]);
    }
    float den = 0.f;
#pragma unroll
    for (int s = 0; s < KVSPLIT; ++s) {
        cs[s] = exp2_fast(cs[s] - m);
        den += Lout[ns[s]] * cs[s];
    }
    float inv = 1.f / den;
#pragma unroll
    for (int s = 0; s < KVSPLIT; ++s) cs[s] *= inv;

    u16* ab = attnoB + ((size_t)b * N_TOK + i) * CI_DIM;
#pragma unroll
    for (int g = 0; g < 4; ++g) {
        float acc[8];
#pragma unroll
        for (int e = 0; e < 8; ++e) acc[e] = 0.f;
#pragma unroll
        for (int s = 0; s < KVSPLIT; ++s) {
            u16x8 ov = *(const u16x8*)&Opart[ns[s] * CI_DIM + c0 + g * 8];
#pragma unroll
            for (int e = 0; e < 8; ++e) acc[e] += bf2f(ov[e]) * cs[s];
        }
        u16x8 res;
#pragma unroll
        for (int e = 0; e < 8; ++e) res[e] = f2bf(acc[e]);
        *(u16x8*)&ab[c0 + g * 8] = res;
    }
}

// ---------------------------------------------------------------------------
// Kernel D: output projection via MFMA + bias + residual, fp32 out.
// attnoB B-tile staged through LDS (coalesced load + ds_read_b128 fragments)
// instead of 16-cache-line scattered global fragment reads.
// grid = (64 n-tiles of 64, B), block = 256.
// ---------------------------------------------------------------------------
__global__ __launch_bounds__(256) void out_gemm_kernel(
    const u16* __restrict__ attnoB,  // [B][N][CI] bf16
    const u16* __restrict__ woB,     // [C][CI] bf16
    const float* __restrict__ bo,    // [C]
    const float* __restrict__ x,     // [B][C][N]
    float* __restrict__ out)         // [B][C][N]
{
    const int n0 = blockIdx.x * 64;
    const int b  = blockIdx.y;
    const int t  = threadIdx.x;
    const int w  = t >> 6;
    const int l  = t & 63;
    const int lg = l >> 4;
    const int li = l & 15;
    const int co0 = w * 128;

    __shared__ u16 Bs[64][136];      // B tile (17-quad rows, conflict-benign)

    // stage attnoB tile: thread t -> row r=t>>2, 32-col chunk (t&3)*32
    {
        const int r  = t >> 2;
        const int cb = (t & 3) * 32;
        const u16* src = attnoB + ((size_t)b * N_TOK + n0 + r) * CI_DIM + cb;
#pragma unroll
        for (int g = 0; g < 4; ++g)
            *(u16x8a*)&Bs[r][cb + g * 8] = *(const u16x8a*)&src[g * 8];
    }
    __syncthreads();

    f32x4 acc[8][4];
#pragma unroll
    for (int m = 0; m < 8; ++m)
#pragma unroll
        for (int j = 0; j < 4; ++j)
#pragma unroll
            for (int r = 0; r < 4; ++r) acc[m][j][r] = 0.f;

    const u16* Abase = woB + (size_t)(co0 + li) * CI_DIM + lg * 8;

#pragma unroll
    for (int kk = 0; kk < 4; ++kk) {
        bf16x8 af[8], bfv[4];
#pragma unroll
        for (int m = 0; m < 8; ++m)
            af[m] = *(const bf16x8*)&Abase[(size_t)(m * 16) * CI_DIM + kk * 32];
#pragma unroll
        for (int j = 0; j < 4; ++j)
            bfv[j] = *(const bf16x8a*)&Bs[j * 16 + li][kk * 32 + lg * 8];
        __builtin_amdgcn_s_setprio(1);
#pragma unroll
        for (int m = 0; m < 8; ++m)
#pragma unroll
            for (int j = 0; j < 4; ++j)
                acc[m][j] = __builtin_amdgcn_mfma_f32_16x16x32_bf16(
                    af[m], bfv[j], acc[m][j], 0, 0, 0);
        __builtin_amdgcn_s_setprio(0);
    }

    const size_t base = (size_t)b * C_DIM * N_TOK;
#pragma unroll
    for (int m = 0; m < 8; ++m)
#pragma unroll
        for (int r = 0; r < 4; ++r) {
            int co = co0 + m * 16 + lg * 4 + r;
            float bia = bo[co];
#pragma unroll
            for (int j = 0; j < 4; ++j) {
                size_t idx = base + (size_t)co * N_TOK + n0 + j * 16 + li;
                out[idx] = acc[m][j][r] + bia + x[idx];
            }
        }
}

extern "C" void kernel_launch(void* const* d_in, const int* in_sizes, int n_in,
                              void* d_out, int out_size, void* d_ws, size_t ws_size,
                              hipStream_t stream) {
    const float* x  = (const float*)d_in[0];
    const float* wq = (const float*)d_in[1];
    const float* bq = (const float*)d_in[2];
    const float* wk = (const float*)d_in[3];
    const float* bk = (const float*)d_in[4];
    const float* wv = (const float*)d_in[5];
    const float* bv = (const float*)d_in[6];
    const float* wo = (const float*)d_in[7];
    const float* bo = (const float*)d_in[8];
    float* out = (float*)d_out;

    // workspace layout (bytes):
    //  [0,16M)         xT bf16 [B][N][C]  -- dead after qkv_gemm; reused as
    //                  Opart bf16 [4][B][N][CI] (exactly 16 MB)
    //  [16M,16.5M)     wqB/wkB/wvB/woB bf16 (128K each)
    //  [16.5M,20.5M)   qT bf16 [B][N][CI]
    //  [20.5M,24.5M)   kT bf16 [B][N][CI]
    //  [24.5M,28.5M)   vB bf16 [B][CI][N]
    //  [28.5M,+512K)   Mout/Lout f32 [4][B][N] (256K each)
    //  [29M,33M)       attnoB bf16 [B][N][CI]
    char* ws = (char*)d_ws;
    const size_t MB = 1024 * 1024;
    u16*   xT    = (u16*)(ws);
    u16*   Opart = (u16*)(ws);                   // aliases xT (16 MB, exact)
    u16*   wqB   = (u16*)(ws + 16 * MB);
    u16*   wkB   = (u16*)(ws + 16 * MB + 128 * 1024);
    u16*   wvB   = (u16*)(ws + 16 * MB + 256 * 1024);
    u16*   woB   = (u16*)(ws + 16 * MB + 384 * 1024);
    u16*   qT    = (u16*)(ws + 16 * MB + 512 * 1024);
    u16*   kT    = (u16*)(ws + 20 * MB + 512 * 1024);
    u16*   vB    = (u16*)(ws + 24 * MB + 512 * 1024);
    float* Mout  = (float*)(ws + 28 * MB + 512 * 1024);
    float* Lout  = (float*)(ws + 28 * MB + 768 * 1024);
    u16*  attnoB = (u16*)(ws + 29 * MB);

    xpose_kernel<<<dim3(64, 8, 4), 256, 0, stream>>>(x, xT);
    wconv_kernel<<<dim3(32, 4), 256, 0, stream>>>(
        wq, wk, wv, wo, wqB, wkB, wvB, woB);
    qkv_gemm_kernel<<<dim3(32, 4, 3), 256, 0, stream>>>(
        xT, wqB, wkB, wvB, bq, bk, bv, qT, kT, vB);
    attn_mfma_kernel<<<dim3(512), 256, 0, stream>>>(
        qT, kT, vB, Opart, Mout, Lout);
    attn_merge_kernel<<<dim3(64, 4), 256, 0, stream>>>(
        Opart, Mout, Lout, attnoB);
    out_gemm_kernel<<<dim3(64, 4), 256, 0, stream>>>(
        attnoB, woB, bo, x, out);
}

// Round 19
// 104.920 us; speedup vs baseline: 1.1492x; 1.1492x over previous
//
#include <hip/hip_runtime.h>

#define N_TOK 4096
#define C_DIM 512
#define CI_DIM 128
#define B_DIM 4
#define KVSPLIT 4
#define KVBLK 32
#define NIT (N_TOK / KVSPLIT / KVBLK)
#define LOG2E 1.4426950408889634f
#define RESCALE_THR2 11.541560327111708f   /* 8 * log2(e), base-2 units */

typedef unsigned short u16;
typedef unsigned int u32;
typedef unsigned long long u64;
typedef __attribute__((ext_vector_type(8))) short bf16x8;
typedef __attribute__((ext_vector_type(4))) float f32x4;
typedef __attribute__((ext_vector_type(8))) unsigned short u16x8;
typedef __attribute__((ext_vector_type(4))) float float4v;

// alias-safe views of LDS tiles (stored via one type, read via another)
typedef unsigned long long __attribute__((may_alias)) u64a;
typedef bf16x8 __attribute__((may_alias)) bf16x8a;
typedef u16x8 __attribute__((may_alias)) u16x8a;

__device__ __forceinline__ u16 f2bf(float f) {
    union { float f; u32 u; } v; v.f = f;
    u32 r = (v.u + 0x7fffu + ((v.u >> 16) & 1u)) >> 16;
    return (u16)r;
}
__device__ __forceinline__ float bf2f(u16 h) {
    union { u32 u; float f; } v; v.u = (u32)h << 16;
    return v.f;
}
__device__ __forceinline__ u32 cvt_pk_bf16(float a, float b) {
    u32 r;
    asm("v_cvt_pk_bf16_f32 %0, %1, %2" : "=v"(r) : "v"(a), "v"(b));
    return r;
}
// 2^x via the native transcendental (v_exp_f32 computes exp2)
__device__ __forceinline__ float exp2_fast(float a) {
    float r;
    asm("v_exp_f32 %0, %1" : "=v"(r) : "v"(a));
    return r;
}

// ---------------------------------------------------------------------------
// Prepass 1: transpose+convert x f32 [B][C][N] -> xT bf16 [B][N][C]
// ---------------------------------------------------------------------------
__global__ __launch_bounds__(256) void xpose_kernel(
    const float* __restrict__ x, u16* __restrict__ xT)
{
    const int n0 = blockIdx.x * 64;
    const int c0 = blockIdx.y * 64;
    const int b  = blockIdx.z;
    __shared__ u16 Ts[64][72];
    const int t = threadIdx.x;

    const float* xb = x + (size_t)b * C_DIM * N_TOK;
    for (int idx = t; idx < 4096; idx += 256) {
        int c = idx >> 6, n = idx & 63;
        Ts[n][c] = f2bf(xb[(size_t)(c0 + c) * N_TOK + n0 + n]);
    }
    __syncthreads();
    u16* xTb = xT + (size_t)b * N_TOK * C_DIM;
    for (int idx = t; idx < 512; idx += 256) {
        int n = idx >> 3, c8 = idx & 7;
        *(u16x8*)&xTb[(size_t)(n0 + n) * C_DIM + c0 + c8 * 8] =
            *(u16x8*)&Ts[n][c8 * 8];
    }
}

// ---------------------------------------------------------------------------
// Prepass 2: convert weights to bf16 (layouts unchanged).
// ---------------------------------------------------------------------------
__global__ __launch_bounds__(256) void wconv_kernel(
    const float* __restrict__ wq, const float* __restrict__ wk,
    const float* __restrict__ wv, const float* __restrict__ wo,
    u16* __restrict__ wqB, u16* __restrict__ wkB,
    u16* __restrict__ wvB, u16* __restrict__ woB)
{
    const int z = blockIdx.y;
    const float* src = (z == 0) ? wq : (z == 1) ? wk : (z == 2) ? wv : wo;
    u16* dst = (z == 0) ? wqB : (z == 1) ? wkB : (z == 2) ? wvB : woB;
    const int i0 = (blockIdx.x * 256 + threadIdx.x) * 8;
    float4v a = *(const float4v*)&src[i0];
    float4v b = *(const float4v*)&src[i0 + 4];
    u16x8 o;
    o[0] = f2bf(a[0]); o[1] = f2bf(a[1]); o[2] = f2bf(a[2]); o[3] = f2bf(a[3]);
    o[4] = f2bf(b[0]); o[5] = f2bf(b[1]); o[6] = f2bf(b[2]); o[7] = f2bf(b[3]);
    *(u16x8*)&dst[i0] = o;
}

// ---------------------------------------------------------------------------
// Kernel A: q/k/v projections via MFMA, LDS-staged operand tiles. (r12,
// verified). q output (z==0) is pre-scaled by log2(e) so attention's
// softmax can use bare v_exp (exp2) with no per-element multiply.
// ---------------------------------------------------------------------------
__global__ __launch_bounds__(256) void qkv_gemm_kernel(
    const u16* __restrict__ xT,
    const u16* __restrict__ wqB, const u16* __restrict__ wkB,
    const u16* __restrict__ wvB,
    const float* __restrict__ bq, const float* __restrict__ bk,
    const float* __restrict__ bv,
    u16* __restrict__ qT, u16* __restrict__ kT, u16* __restrict__ vB)
{
    const int n0 = blockIdx.x * 128;
    const int b  = blockIdx.y;
    const int z  = blockIdx.z;
    const u16* wz = (z == 0) ? wqB : (z == 1) ? wkB : wvB;
    const float* bias = (z == 0) ? bq : (z == 1) ? bk : bv;

    __shared__ u16 Xs[128][72];
    __shared__ u16 Ws[128][72];

    const int t  = threadIdx.x;
    const int w  = t >> 6;
    const int l  = t & 63;
    const int lg = l >> 4;
    const int li = l & 15;
    const int cb = w * 32;

    const u16* xTb = xT + (size_t)b * N_TOK * C_DIM;

    const int srow = t >> 1;
    const int sh   = (t & 1) * 32;

    f32x4 acc[8][2];
#pragma unroll
    for (int m = 0; m < 8; ++m)
#pragma unroll
        for (int j = 0; j < 2; ++j)
#pragma unroll
            for (int r = 0; r < 4; ++r) acc[m][j][r] = 0.f;

    u16x8 xv[4], wv[4];
#pragma unroll
    for (int g = 0; g < 4; ++g) {
        xv[g] = *(const u16x8a*)&xTb[(size_t)(n0 + srow) * C_DIM + sh + g * 8];
        wv[g] = *(const u16x8a*)&wz[(size_t)srow * C_DIM + sh + g * 8];
    }

    const u16 (*A_lds)[72] = (z < 2) ? Xs : Ws;
    const u16 (*B_lds)[72] = (z < 2) ? Ws : Xs;

#pragma unroll 1
    for (int kk = 0; kk < C_DIM / 64; ++kk) {
        __syncthreads();
#pragma unroll
        for (int g = 0; g < 4; ++g) {
            *(u16x8a*)&Xs[srow][sh + g * 8] = xv[g];
            *(u16x8a*)&Ws[srow][sh + g * 8] = wv[g];
        }
        __syncthreads();

        if (kk + 1 < C_DIM / 64) {
            const int k0 = (kk + 1) * 64;
#pragma unroll
            for (int g = 0; g < 4; ++g) {
                xv[g] = *(const u16x8a*)&xTb[(size_t)(n0 + srow) * C_DIM + k0 + sh + g * 8];
                wv[g] = *(const u16x8a*)&wz[(size_t)srow * C_DIM + k0 + sh + g * 8];
            }
        }

#pragma unroll
        for (int kc = 0; kc < 2; ++kc) {
            bf16x8 af[8], bfv[2];
#pragma unroll
            for (int m = 0; m < 8; ++m)
                af[m] = *(const bf16x8a*)&A_lds[m * 16 + li][kc * 32 + lg * 8];
#pragma unroll
            for (int j = 0; j < 2; ++j)
                bfv[j] = *(const bf16x8a*)&B_lds[cb + j * 16 + li][kc * 32 + lg * 8];
            __builtin_amdgcn_s_setprio(1);
#pragma unroll
            for (int m = 0; m < 8; ++m)
#pragma unroll
                for (int j = 0; j < 2; ++j)
                    acc[m][j] = __builtin_amdgcn_mfma_f32_16x16x32_bf16(
                        af[m], bfv[j], acc[m][j], 0, 0, 0);
            __builtin_amdgcn_s_setprio(0);
        }
    }

    if (z < 2) {
        u16* dst = ((z == 0) ? qT : kT) + (size_t)b * N_TOK * CI_DIM;
        const float osc = (z == 0) ? LOG2E : 1.0f;   // pre-scale q by log2(e)
#pragma unroll
        for (int j = 0; j < 2; ++j) {
            float bia = bias[cb + j * 16 + li];
#pragma unroll
            for (int m = 0; m < 8; ++m)
#pragma unroll
                for (int r = 0; r < 4; ++r)
                    dst[(size_t)(n0 + m * 16 + lg * 4 + r) * CI_DIM + cb + j * 16 + li] =
                        f2bf((acc[m][j][r] + bia) * osc);
        }
    } else {
        u16* dst = vB + (size_t)b * CI_DIM * N_TOK;
#pragma unroll
        for (int m = 0; m < 8; ++m)
#pragma unroll
            for (int r = 0; r < 4; ++r) {
                int o = m * 16 + lg * 4 + r;
                float bia = bias[o];
#pragma unroll
                for (int j = 0; j < 2; ++j)
                    dst[(size_t)o * N_TOK + n0 + cb + j * 16 + li] =
                        f2bf(acc[m][j][r] + bia);
            }
    }
}

// ---------------------------------------------------------------------------
// Kernel B: MFMA flash attention (r12 structure + base-2 softmax, verified
// 60.2us in r18). grid = 512 blocks 1-D; combo = x&15 (XCD swizzle).
// ---------------------------------------------------------------------------
__global__ __launch_bounds__(256) void attn_mfma_kernel(
    const u16* __restrict__ qT,   // [B][N][CI] (pre-scaled by log2e)
    const u16* __restrict__ kT,   // [B][N][CI]
    const u16* __restrict__ vB,   // [B][CI][N]
    u16* __restrict__ Opart,      // [4][B][N][CI] bf16, unnormalized
    float* __restrict__ Mout,     // [4][B][N] (base-2 units)
    float* __restrict__ Lout)     // [4][B][N]
{
    const int x   = blockIdx.x;
    const int qb  = x >> 4;         // [0,32)
    const int b   = x & 3;          // combo = x & 15 -> same XCD per combo
    const int kvh = (x >> 2) & 3;
    const int j_beg = kvh * (N_TOK / KVSPLIT);

    __shared__ u16 Ks[KVBLK][152];   // K tile, token-major (19-quad stride)
    __shared__ u16 Vs[CI_DIM][56];   // V tile, channel-major (7-quad stride)
    __shared__ u16 Ps[4][32][40];    // per-wave P tile (5-quad stride)

    const int t  = threadIdx.x;
    const int w  = t >> 6;
    const int l  = t & 63;
    const int lg = l >> 4;
    const int li = l & 15;
    const int qw = qb * 128 + w * 32;   // this wave's first query row

    // staging coordinates (coalesced global reads)
    const int krow = t >> 3, kc8 = t & 7;    // K: 32 rows x 8 chunks of 16 u16
    const int vch  = t >> 1, vh  = t & 1;    // V: 128 ch x 2 chunks of 16 u16

    const u16* qTb = qT + (size_t)b * N_TOK * CI_DIM;
    const u16* kTb = kT + (size_t)b * N_TOK * CI_DIM;
    const u16* vBb = vB + (size_t)b * CI_DIM * N_TOK;

    // Q fragments direct from global (once)
    bf16x8 qf[2][4];
#pragma unroll
    for (int qt = 0; qt < 2; ++qt)
#pragma unroll
        for (int kc = 0; kc < 4; ++kc)
            qf[qt][kc] = *(const bf16x8*)&qTb[(size_t)(qw + qt * 16 + li) * CI_DIM + kc * 32 + lg * 8];

    f32x4 Oacc[2][8];
#pragma unroll
    for (int qt = 0; qt < 2; ++qt)
#pragma unroll
        for (int ct = 0; ct < 8; ++ct)
#pragma unroll
            for (int r = 0; r < 4; ++r) Oacc[qt][ct][r] = 0.f;

    float mrun[2] = {-1e30f, -1e30f};
    float lrun[2] = {0.f, 0.f};     // per-lane partials

    // prologue: prefetch tile 0 into regs
    u16x8 kv0, kv1, vv0, vv1;
    {
        const u16* ksrc = &kTb[(size_t)(j_beg + krow) * CI_DIM + kc8 * 16];
        kv0 = *(const u16x8a*)&ksrc[0];
        kv1 = *(const u16x8a*)&ksrc[8];
        const u16* vsrc = &vBb[(size_t)vch * N_TOK + j_beg + vh * 16];
        vv0 = *(const u16x8a*)&vsrc[0];
        vv1 = *(const u16x8a*)&vsrc[8];
    }

#pragma unroll 1
    for (int it = 0; it < NIT; ++it) {
        // (A) all waves done reading previous tile
        __syncthreads();
        *(u16x8a*)&Ks[krow][kc8 * 16]     = kv0;
        *(u16x8a*)&Ks[krow][kc8 * 16 + 8] = kv1;
        *(u16x8a*)&Vs[vch][vh * 16]       = vv0;
        *(u16x8a*)&Vs[vch][vh * 16 + 8]   = vv1;
        // (B) tile ready
        __syncthreads();

        // prefetch next tile into regs; latency hides under compute below
        if (it + 1 < NIT) {
            const int jn = j_beg + (it + 1) * KVBLK;
            const u16* ksrc = &kTb[(size_t)(jn + krow) * CI_DIM + kc8 * 16];
            kv0 = *(const u16x8a*)&ksrc[0];
            kv1 = *(const u16x8a*)&ksrc[8];
            const u16* vsrc = &vBb[(size_t)vch * N_TOK + jn + vh * 16];
            vv0 = *(const u16x8a*)&vsrc[0];
            vv1 = *(const u16x8a*)&vsrc[8];
        }

        // ---- QK^T (swapped): S^T[j][i], fragments from LDS
        bf16x8 ak[2][4];
#pragma unroll
        for (int jt = 0; jt < 2; ++jt)
#pragma unroll
            for (int kc = 0; kc < 4; ++kc)
                ak[jt][kc] = *(const bf16x8a*)&Ks[jt * 16 + li][kc * 32 + lg * 8];

        f32x4 sacc[2][2];
#pragma unroll
        for (int qt = 0; qt < 2; ++qt)
#pragma unroll
            for (int jt = 0; jt < 2; ++jt)
#pragma unroll
                for (int r = 0; r < 4; ++r) sacc[qt][jt][r] = 0.f;
        __builtin_amdgcn_s_setprio(1);
#pragma unroll
        for (int jt = 0; jt < 2; ++jt)
#pragma unroll
            for (int kc = 0; kc < 4; ++kc) {
                sacc[0][jt] = __builtin_amdgcn_mfma_f32_16x16x32_bf16(ak[jt][kc], qf[0][kc], sacc[0][jt], 0, 0, 0);
                sacc[1][jt] = __builtin_amdgcn_mfma_f32_16x16x32_bf16(ak[jt][kc], qf[1][kc], sacc[1][jt], 0, 0, 0);
            }
        __builtin_amdgcn_s_setprio(0);

        // ---- softmax (base-2): shuffle-free common path (defer-max)
#pragma unroll
        for (int qt = 0; qt < 2; ++qt) {
            float tl = sacc[qt][0][0];
#pragma unroll
            for (int jt = 0; jt < 2; ++jt)
#pragma unroll
                for (int r = 0; r < 4; ++r) tl = fmaxf(tl, sacc[qt][jt][r]);

            if (__any(tl > mrun[qt] + RESCALE_THR2)) {
                float tmax = fmaxf(tl, __shfl_xor(tl, 16));
                tmax = fmaxf(tmax, __shfl_xor(tmax, 32));
                float mold = mrun[qt];
                float mnew = fmaxf(mold, tmax);
                float scale = exp2_fast(mold - mnew);
                lrun[qt] *= scale;
                mrun[qt] = mnew;
#pragma unroll
                for (int r = 0; r < 4; ++r) {
                    float sc_r = __shfl(scale, lg * 4 + r);
#pragma unroll
                    for (int ct = 0; ct < 8; ++ct) Oacc[qt][ct][r] *= sc_r;
                }
            }
            float m = mrun[qt];
            float psum = 0.f;
#pragma unroll
            for (int jt = 0; jt < 2; ++jt) {
                float p0 = exp2_fast(sacc[qt][jt][0] - m);
                float p1 = exp2_fast(sacc[qt][jt][1] - m);
                float p2 = exp2_fast(sacc[qt][jt][2] - m);
                float p3 = exp2_fast(sacc[qt][jt][3] - m);
                psum += (p0 + p1) + (p2 + p3);
                u32 lo = cvt_pk_bf16(p0, p1);
                u32 hi = cvt_pk_bf16(p2, p3);
                u64 pk = (u64)lo | ((u64)hi << 32);
                *(u64a*)&Ps[w][qt * 16 + li][jt * 16 + lg * 4] = pk;
            }
            lrun[qt] += psum;
        }

        // order P stores before PV reads
        asm volatile("" ::: "memory");

        // ---- PV: O^T[i][c] += P[i][j] * V^T[j][c]  (K=32, one slice)
        bf16x8 ap0 = *(const bf16x8a*)&Ps[w][li][lg * 8];
        bf16x8 ap1 = *(const bf16x8a*)&Ps[w][16 + li][lg * 8];
        __builtin_amdgcn_s_setprio(1);
#pragma unroll
        for (int ct = 0; ct < 8; ++ct) {
            bf16x8 bv = *(const bf16x8a*)&Vs[ct * 16 + li][lg * 8];
            Oacc[0][ct] = __builtin_amdgcn_mfma_f32_16x16x32_bf16(ap0, bv, Oacc[0][ct], 0, 0, 0);
            Oacc[1][ct] = __builtin_amdgcn_mfma_f32_16x16x32_bf16(ap1, bv, Oacc[1][ct], 0, 0, 0);
        }
        __builtin_amdgcn_s_setprio(0);
    }

    // ---- epilogue: finish l (cross-lane reduce), write m/l + bf16 O partial
#pragma unroll
    for (int qt = 0; qt < 2; ++qt) {
        lrun[qt] += __shfl_xor(lrun[qt], 16);
        lrun[qt] += __shfl_xor(lrun[qt], 32);
    }
    const size_t mlbase = ((size_t)kvh * B_DIM + b) * N_TOK + qw;
    if (lg == 0) {
#pragma unroll
        for (int qt = 0; qt < 2; ++qt) {
            Mout[mlbase + qt * 16 + li] = mrun[qt];
            Lout[mlbase + qt * 16 + li] = lrun[qt];
        }
    }
    u16* Ob = Opart + mlbase * CI_DIM;
#pragma unroll
    for (int qt = 0; qt < 2; ++qt)
#pragma unroll
        for (int ct = 0; ct < 8; ++ct)
#pragma unroll
            for (int r = 0; r < 4; ++r)
                Ob[(size_t)(qt * 16 + lg * 4 + r) * CI_DIM + ct * 16 + li] =
                    f2bf(Oacc[qt][ct][r]);
}

// ---------------------------------------------------------------------------
// Kernel C: merge the 4 KV-quarter partials -> attnoB bf16 [B][N][CI]
// (m-deltas are base-2 -> exp2_fast)
// ---------------------------------------------------------------------------
__global__ __launch_bounds__(256) void attn_merge_kernel(
    const u16* __restrict__ Opart, const float* __restrict__ Mout,
    const float* __restrict__ Lout, u16* __restrict__ attnoB)
{
    const int qb = blockIdx.x;
    const int b  = blockIdx.y;
    const int t  = threadIdx.x;
    const int i  = qb * 64 + (t & 63);
    const int c0 = (t >> 6) * 32;

    size_t ns[KVSPLIT];
    float cs[KVSPLIT];
    float m = -1e30f;
#pragma unroll
    for (int s = 0; s < KVSPLIT; ++s) {
        ns[s] = ((size_t)s * B_DIM + b) * N_TOK + i;
        cs[s] = Mout[ns[s]];
        m = fmaxf(m, cs[s]);
    }
    float den = 0.f;
#pragma unroll
    for (int s = 0; s < KVSPLIT; ++s) {
        cs[s] = exp2_fast(cs[s] - m);
        den += Lout[ns[s]] * cs[s];
    }
    float inv = 1.f / den;
#pragma unroll
    for (int s = 0; s < KVSPLIT; ++s) cs[s] *= inv;

    u16* ab = attnoB + ((size_t)b * N_TOK + i) * CI_DIM;
#pragma unroll
    for (int g = 0; g < 4; ++g) {
        float acc[8];
#pragma unroll
        for (int e = 0; e < 8; ++e) acc[e] = 0.f;
#pragma unroll
        for (int s = 0; s < KVSPLIT; ++s) {
            u16x8 ov = *(const u16x8*)&Opart[ns[s] * CI_DIM + c0 + g * 8];
#pragma unroll
            for (int e = 0; e < 8; ++e) acc[e] += bf2f(ov[e]) * cs[s];
        }
        u16x8 res;
#pragma unroll
        for (int e = 0; e < 8; ++e) res[e] = f2bf(acc[e]);
        *(u16x8*)&ab[c0 + g * 8] = res;
    }
}

// ---------------------------------------------------------------------------
// Kernel D: output projection via MFMA + bias + residual, fp32 out.
// (r12 verbatim: plain global B reads — this kernel is HBM-bound (~68MB
// traffic); r15/r18 both proved LDS staging of B only adds overhead.)
// ---------------------------------------------------------------------------
__global__ __launch_bounds__(256) void out_gemm_kernel(
    const u16* __restrict__ attnoB,  // [B][N][CI] bf16
    const u16* __restrict__ woB,     // [C][CI] bf16
    const float* __restrict__ bo,    // [C]
    const float* __restrict__ x,     // [B][C][N]
    float* __restrict__ out)         // [B][C][N]
{
    const int n0 = blockIdx.x * 64;
    const int b  = blockIdx.y;
    const int t  = threadIdx.x;
    const int w  = t >> 6;
    const int l  = t & 63;
    const int lg = l >> 4;
    const int li = l & 15;
    const int co0 = w * 128;

    const u16* ab = attnoB + (size_t)b * N_TOK * CI_DIM;

    f32x4 acc[8][4];
#pragma unroll
    for (int m = 0; m < 8; ++m)
#pragma unroll
        for (int j = 0; j < 4; ++j)
#pragma unroll
            for (int r = 0; r < 4; ++r) acc[m][j][r] = 0.f;

    const u16* Abase = woB + (size_t)(co0 + li) * CI_DIM + lg * 8;
    const u16* Bbase = ab + (size_t)(n0 + li) * CI_DIM + lg * 8;

#pragma unroll
    for (int kk = 0; kk < 4; ++kk) {
        bf16x8 af[8], bfv[4];
#pragma unroll
        for (int m = 0; m < 8; ++m)
            af[m] = *(const bf16x8*)&Abase[(size_t)(m * 16) * CI_DIM + kk * 32];
#pragma unroll
        for (int j = 0; j < 4; ++j)
            bfv[j] = *(const bf16x8*)&Bbase[(size_t)(j * 16) * CI_DIM + kk * 32];
#pragma unroll
        for (int m = 0; m < 8; ++m)
#pragma unroll
            for (int j = 0; j < 4; ++j)
                acc[m][j] = __builtin_amdgcn_mfma_f32_16x16x32_bf16(
                    af[m], bfv[j], acc[m][j], 0, 0, 0);
    }

    const size_t base = (size_t)b * C_DIM * N_TOK;
#pragma unroll
    for (int m = 0; m < 8; ++m)
#pragma unroll
        for (int r = 0; r < 4; ++r) {
            int co = co0 + m * 16 + lg * 4 + r;
            float bia = bo[co];
#pragma unroll
            for (int j = 0; j < 4; ++j) {
                size_t idx = base + (size_t)co * N_TOK + n0 + j * 16 + li;
                out[idx] = acc[m][j][r] + bia + x[idx];
            }
        }
}

extern "C" void kernel_launch(void* const* d_in, const int* in_sizes, int n_in,
                              void* d_out, int out_size, void* d_ws, size_t ws_size,
                              hipStream_t stream) {
    const float* x  = (const float*)d_in[0];
    const float* wq = (const float*)d_in[1];
    const float* bq = (const float*)d_in[2];
    const float* wk = (const float*)d_in[3];
    const float* bk = (const float*)d_in[4];
    const float* wv = (const float*)d_in[5];
    const float* bv = (const float*)d_in[6];
    const float* wo = (const float*)d_in[7];
    const float* bo = (const float*)d_in[8];
    float* out = (float*)d_out;

    // workspace layout (bytes):
    //  [0,16M)         xT bf16 [B][N][C]  -- dead after qkv_gemm; reused as
    //                  Opart bf16 [4][B][N][CI] (exactly 16 MB)
    //  [16M,16.5M)     wqB/wkB/wvB/woB bf16 (128K each)
    //  [16.5M,20.5M)   qT bf16 [B][N][CI]
    //  [20.5M,24.5M)   kT bf16 [B][N][CI]
    //  [24.5M,28.5M)   vB bf16 [B][CI][N]
    //  [28.5M,+512K)   Mout/Lout f32 [4][B][N] (256K each)
    //  [29M,33M)       attnoB bf16 [B][N][CI]
    char* ws = (char*)d_ws;
    const size_t MB = 1024 * 1024;
    u16*   xT    = (u16*)(ws);
    u16*   Opart = (u16*)(ws);                   // aliases xT (16 MB, exact)
    u16*   wqB   = (u16*)(ws + 16 * MB);
    u16*   wkB   = (u16*)(ws + 16 * MB + 128 * 1024);
    u16*   wvB   = (u16*)(ws + 16 * MB + 256 * 1024);
    u16*   woB   = (u16*)(ws + 16 * MB + 384 * 1024);
    u16*   qT    = (u16*)(ws + 16 * MB + 512 * 1024);
    u16*   kT    = (u16*)(ws + 20 * MB + 512 * 1024);
    u16*   vB    = (u16*)(ws + 24 * MB + 512 * 1024);
    float* Mout  = (float*)(ws + 28 * MB + 512 * 1024);
    float* Lout  = (float*)(ws + 28 * MB + 768 * 1024);
    u16*  attnoB = (u16*)(ws + 29 * MB);

    xpose_kernel<<<dim3(64, 8, 4), 256, 0, stream>>>(x, xT);
    wconv_kernel<<<dim3(32, 4), 256, 0, stream>>>(
        wq, wk, wv, wo, wqB, wkB, wvB, woB);
    qkv_gemm_kernel<<<dim3(32, 4, 3), 256, 0, stream>>>(
        xT, wqB, wkB, wvB, bq, bk, bv, qT, kT, vB);
    attn_mfma_kernel<<<dim3(512), 256, 0, stream>>>(
        qT, kT, vB, Opart, Mout, Lout);
    attn_merge_kernel<<<dim3(64, 4), 256, 0, stream>>>(
        Opart, Mout, Lout, attnoB);
    out_gemm_kernel<<<dim3(64, 4), 256, 0, stream>>>(
        attnoB, woB, bo, x, out);
}

// Round 20
// 104.651 us; speedup vs baseline: 1.1522x; 1.0026x over previous
//
#include <hip/hip_runtime.h>

#define N_TOK 4096
#define C_DIM 512
#define CI_DIM 128
#define B_DIM 4
#define KVSPLIT 4
#define KVBLK 32
#define NIT (N_TOK / KVSPLIT / KVBLK)
#define LOG2E 1.4426950408889634f
#define RESCALE_THR2 11.541560327111708f   /* 8 * log2(e), base-2 units */

typedef unsigned short u16;
typedef unsigned int u32;
typedef unsigned long long u64;
typedef __attribute__((ext_vector_type(8))) short bf16x8;
typedef __attribute__((ext_vector_type(4))) float f32x4;
typedef __attribute__((ext_vector_type(8))) unsigned short u16x8;
typedef __attribute__((ext_vector_type(4))) float float4v;

// alias-safe views of LDS tiles (stored via one type, read via another)
typedef unsigned long long __attribute__((may_alias)) u64a;
typedef bf16x8 __attribute__((may_alias)) bf16x8a;
typedef u16x8 __attribute__((may_alias)) u16x8a;

__device__ __forceinline__ u16 f2bf(float f) {
    union { float f; u32 u; } v; v.f = f;
    u32 r = (v.u + 0x7fffu + ((v.u >> 16) & 1u)) >> 16;
    return (u16)r;
}
__device__ __forceinline__ float bf2f(u16 h) {
    union { u32 u; float f; } v; v.u = (u32)h << 16;
    return v.f;
}
__device__ __forceinline__ u32 cvt_pk_bf16(float a, float b) {
    u32 r;
    asm("v_cvt_pk_bf16_f32 %0, %1, %2" : "=v"(r) : "v"(a), "v"(b));
    return r;
}
// 2^x via the native transcendental (v_exp_f32 computes exp2)
__device__ __forceinline__ float exp2_fast(float a) {
    float r;
    asm("v_exp_f32 %0, %1" : "=v"(r) : "v"(a));
    return r;
}

// ---------------------------------------------------------------------------
// Prepass 1: transpose+convert x f32 [B][C][N] -> xT bf16 [B][N][C]
// ---------------------------------------------------------------------------
__global__ __launch_bounds__(256) void xpose_kernel(
    const float* __restrict__ x, u16* __restrict__ xT)
{
    const int n0 = blockIdx.x * 64;
    const int c0 = blockIdx.y * 64;
    const int b  = blockIdx.z;
    __shared__ u16 Ts[64][72];
    const int t = threadIdx.x;

    const float* xb = x + (size_t)b * C_DIM * N_TOK;
    for (int idx = t; idx < 4096; idx += 256) {
        int c = idx >> 6, n = idx & 63;
        Ts[n][c] = f2bf(xb[(size_t)(c0 + c) * N_TOK + n0 + n]);
    }
    __syncthreads();
    u16* xTb = xT + (size_t)b * N_TOK * C_DIM;
    for (int idx = t; idx < 512; idx += 256) {
        int n = idx >> 3, c8 = idx & 7;
        *(u16x8*)&xTb[(size_t)(n0 + n) * C_DIM + c0 + c8 * 8] =
            *(u16x8*)&Ts[n][c8 * 8];
    }
}

// ---------------------------------------------------------------------------
// Prepass 2: convert weights to bf16 (layouts unchanged).
// ---------------------------------------------------------------------------
__global__ __launch_bounds__(256) void wconv_kernel(
    const float* __restrict__ wq, const float* __restrict__ wk,
    const float* __restrict__ wv, const float* __restrict__ wo,
    u16* __restrict__ wqB, u16* __restrict__ wkB,
    u16* __restrict__ wvB, u16* __restrict__ woB)
{
    const int z = blockIdx.y;
    const float* src = (z == 0) ? wq : (z == 1) ? wk : (z == 2) ? wv : wo;
    u16* dst = (z == 0) ? wqB : (z == 1) ? wkB : (z == 2) ? wvB : woB;
    const int i0 = (blockIdx.x * 256 + threadIdx.x) * 8;
    float4v a = *(const float4v*)&src[i0];
    float4v b = *(const float4v*)&src[i0 + 4];
    u16x8 o;
    o[0] = f2bf(a[0]); o[1] = f2bf(a[1]); o[2] = f2bf(a[2]); o[3] = f2bf(a[3]);
    o[4] = f2bf(b[0]); o[5] = f2bf(b[1]); o[6] = f2bf(b[2]); o[7] = f2bf(b[3]);
    *(u16x8*)&dst[i0] = o;
}

// ---------------------------------------------------------------------------
// Kernel A: q/k/v projections via MFMA, LDS-staged operand tiles. (verified)
// q output (z==0) is pre-scaled by log2(e) -> attention softmax uses bare
// v_exp (exp2) with no per-element multiply.
// ---------------------------------------------------------------------------
__global__ __launch_bounds__(256) void qkv_gemm_kernel(
    const u16* __restrict__ xT,
    const u16* __restrict__ wqB, const u16* __restrict__ wkB,
    const u16* __restrict__ wvB,
    const float* __restrict__ bq, const float* __restrict__ bk,
    const float* __restrict__ bv,
    u16* __restrict__ qT, u16* __restrict__ kT, u16* __restrict__ vB)
{
    const int n0 = blockIdx.x * 128;
    const int b  = blockIdx.y;
    const int z  = blockIdx.z;
    const u16* wz = (z == 0) ? wqB : (z == 1) ? wkB : wvB;
    const float* bias = (z == 0) ? bq : (z == 1) ? bk : bv;

    __shared__ u16 Xs[128][72];
    __shared__ u16 Ws[128][72];

    const int t  = threadIdx.x;
    const int w  = t >> 6;
    const int l  = t & 63;
    const int lg = l >> 4;
    const int li = l & 15;
    const int cb = w * 32;

    const u16* xTb = xT + (size_t)b * N_TOK * C_DIM;

    const int srow = t >> 1;
    const int sh   = (t & 1) * 32;

    f32x4 acc[8][2];
#pragma unroll
    for (int m = 0; m < 8; ++m)
#pragma unroll
        for (int j = 0; j < 2; ++j)
#pragma unroll
            for (int r = 0; r < 4; ++r) acc[m][j][r] = 0.f;

    u16x8 xv[4], wv[4];
#pragma unroll
    for (int g = 0; g < 4; ++g) {
        xv[g] = *(const u16x8a*)&xTb[(size_t)(n0 + srow) * C_DIM + sh + g * 8];
        wv[g] = *(const u16x8a*)&wz[(size_t)srow * C_DIM + sh + g * 8];
    }

    const u16 (*A_lds)[72] = (z < 2) ? Xs : Ws;
    const u16 (*B_lds)[72] = (z < 2) ? Ws : Xs;

#pragma unroll 1
    for (int kk = 0; kk < C_DIM / 64; ++kk) {
        __syncthreads();
#pragma unroll
        for (int g = 0; g < 4; ++g) {
            *(u16x8a*)&Xs[srow][sh + g * 8] = xv[g];
            *(u16x8a*)&Ws[srow][sh + g * 8] = wv[g];
        }
        __syncthreads();

        if (kk + 1 < C_DIM / 64) {
            const int k0 = (kk + 1) * 64;
#pragma unroll
            for (int g = 0; g < 4; ++g) {
                xv[g] = *(const u16x8a*)&xTb[(size_t)(n0 + srow) * C_DIM + k0 + sh + g * 8];
                wv[g] = *(const u16x8a*)&wz[(size_t)srow * C_DIM + k0 + sh + g * 8];
            }
        }

#pragma unroll
        for (int kc = 0; kc < 2; ++kc) {
            bf16x8 af[8], bfv[2];
#pragma unroll
            for (int m = 0; m < 8; ++m)
                af[m] = *(const bf16x8a*)&A_lds[m * 16 + li][kc * 32 + lg * 8];
#pragma unroll
            for (int j = 0; j < 2; ++j)
                bfv[j] = *(const bf16x8a*)&B_lds[cb + j * 16 + li][kc * 32 + lg * 8];
            __builtin_amdgcn_s_setprio(1);
#pragma unroll
            for (int m = 0; m < 8; ++m)
#pragma unroll
                for (int j = 0; j < 2; ++j)
                    acc[m][j] = __builtin_amdgcn_mfma_f32_16x16x32_bf16(
                        af[m], bfv[j], acc[m][j], 0, 0, 0);
            __builtin_amdgcn_s_setprio(0);
        }
    }

    if (z < 2) {
        u16* dst = ((z == 0) ? qT : kT) + (size_t)b * N_TOK * CI_DIM;
        const float osc = (z == 0) ? LOG2E : 1.0f;   // pre-scale q by log2(e)
#pragma unroll
        for (int j = 0; j < 2; ++j) {
            float bia = bias[cb + j * 16 + li];
#pragma unroll
            for (int m = 0; m < 8; ++m)
#pragma unroll
                for (int r = 0; r < 4; ++r)
                    dst[(size_t)(n0 + m * 16 + lg * 4 + r) * CI_DIM + cb + j * 16 + li] =
                        f2bf((acc[m][j][r] + bia) * osc);
        }
    } else {
        u16* dst = vB + (size_t)b * CI_DIM * N_TOK;
#pragma unroll
        for (int m = 0; m < 8; ++m)
#pragma unroll
            for (int r = 0; r < 4; ++r) {
                int o = m * 16 + lg * 4 + r;
                float bia = bias[o];
#pragma unroll
                for (int j = 0; j < 2; ++j)
                    dst[(size_t)o * N_TOK + n0 + cb + j * 16 + li] =
                        f2bf(acc[m][j][r] + bia);
            }
    }
}

// ---------------------------------------------------------------------------
// Kernel B: MFMA flash attention (r19 structure + conflict-free staging
// lane assignment). kv0/vv0 now cover the FIRST half of each LDS row,
// kv1/vv1 the second half: write quad-group = (3*krow + kc8) mod 8 ->
// consecutive lanes hit consecutive groups (stride-1 equivalent, free)
// instead of the old (3*krow + 2*kc8) 8-way pattern. Final LDS data layout
// is bit-identical; fragment reads untouched.
// grid = 512 blocks 1-D; x = combo + 16*qb; combo = b + 4*kvh (XCD swizzle).
// ---------------------------------------------------------------------------
__global__ __launch_bounds__(256) void attn_mfma_kernel(
    const u16* __restrict__ qT,   // [B][N][CI] (pre-scaled by log2e)
    const u16* __restrict__ kT,   // [B][N][CI]
    const u16* __restrict__ vB,   // [B][CI][N]
    u16* __restrict__ Opart,      // [4][B][N][CI] bf16, unnormalized
    float* __restrict__ Mout,     // [4][B][N] (base-2 units)
    float* __restrict__ Lout)     // [4][B][N]
{
    const int x   = blockIdx.x;
    const int qb  = x >> 4;         // [0,32)
    const int b   = x & 3;          // combo = x & 15 -> same XCD per combo
    const int kvh = (x >> 2) & 3;
    const int j_beg = kvh * (N_TOK / KVSPLIT);

    __shared__ u16 Ks[KVBLK][152];   // K tile, token-major (19-quad stride)
    __shared__ u16 Vs[CI_DIM][56];   // V tile, channel-major (7-quad stride)
    __shared__ u16 Ps[4][32][40];    // per-wave P tile (5-quad stride)

    const int t  = threadIdx.x;
    const int w  = t >> 6;
    const int l  = t & 63;
    const int lg = l >> 4;
    const int li = l & 15;
    const int qw = qb * 128 + w * 32;   // this wave's first query row

    // staging coordinates (coalesced global reads; split-half chunks)
    const int krow = t >> 3, kc8 = t & 7;    // K: 32 rows x (2 x 8 chunks of 8)
    const int vch  = t >> 1, vh  = t & 1;    // V: 128 ch x (2 x 2 chunks of 8)

    const u16* qTb = qT + (size_t)b * N_TOK * CI_DIM;
    const u16* kTb = kT + (size_t)b * N_TOK * CI_DIM;
    const u16* vBb = vB + (size_t)b * CI_DIM * N_TOK;

    // Q fragments direct from global (once)
    bf16x8 qf[2][4];
#pragma unroll
    for (int qt = 0; qt < 2; ++qt)
#pragma unroll
        for (int kc = 0; kc < 4; ++kc)
            qf[qt][kc] = *(const bf16x8*)&qTb[(size_t)(qw + qt * 16 + li) * CI_DIM + kc * 32 + lg * 8];

    f32x4 Oacc[2][8];
#pragma unroll
    for (int qt = 0; qt < 2; ++qt)
#pragma unroll
        for (int ct = 0; ct < 8; ++ct)
#pragma unroll
            for (int r = 0; r < 4; ++r) Oacc[qt][ct][r] = 0.f;

    float mrun[2] = {-1e30f, -1e30f};
    float lrun[2] = {0.f, 0.f};     // per-lane partials

    // prologue: prefetch tile 0 into regs (split-half chunks)
    u16x8 kv0, kv1, vv0, vv1;
    {
        const u16* ksrc = &kTb[(size_t)(j_beg + krow) * CI_DIM];
        kv0 = *(const u16x8a*)&ksrc[kc8 * 8];
        kv1 = *(const u16x8a*)&ksrc[64 + kc8 * 8];
        const u16* vsrc = &vBb[(size_t)vch * N_TOK + j_beg];
        vv0 = *(const u16x8a*)&vsrc[vh * 8];
        vv1 = *(const u16x8a*)&vsrc[16 + vh * 8];
    }

#pragma unroll 1
    for (int it = 0; it < NIT; ++it) {
        // (A) all waves done reading previous tile
        __syncthreads();
        *(u16x8a*)&Ks[krow][kc8 * 8]      = kv0;
        *(u16x8a*)&Ks[krow][64 + kc8 * 8] = kv1;
        *(u16x8a*)&Vs[vch][vh * 8]        = vv0;
        *(u16x8a*)&Vs[vch][16 + vh * 8]   = vv1;
        // (B) tile ready
        __syncthreads();

        // prefetch next tile into regs; latency hides under compute below
        if (it + 1 < NIT) {
            const int jn = j_beg + (it + 1) * KVBLK;
            const u16* ksrc = &kTb[(size_t)(jn + krow) * CI_DIM];
            kv0 = *(const u16x8a*)&ksrc[kc8 * 8];
            kv1 = *(const u16x8a*)&ksrc[64 + kc8 * 8];
            const u16* vsrc = &vBb[(size_t)vch * N_TOK + jn];
            vv0 = *(const u16x8a*)&vsrc[vh * 8];
            vv1 = *(const u16x8a*)&vsrc[16 + vh * 8];
        }

        // ---- QK^T (swapped): S^T[j][i], fragments from LDS
        bf16x8 ak[2][4];
#pragma unroll
        for (int jt = 0; jt < 2; ++jt)
#pragma unroll
            for (int kc = 0; kc < 4; ++kc)
                ak[jt][kc] = *(const bf16x8a*)&Ks[jt * 16 + li][kc * 32 + lg * 8];

        f32x4 sacc[2][2];
#pragma unroll
        for (int qt = 0; qt < 2; ++qt)
#pragma unroll
            for (int jt = 0; jt < 2; ++jt)
#pragma unroll
                for (int r = 0; r < 4; ++r) sacc[qt][jt][r] = 0.f;
        __builtin_amdgcn_s_setprio(1);
#pragma unroll
        for (int jt = 0; jt < 2; ++jt)
#pragma unroll
            for (int kc = 0; kc < 4; ++kc) {
                sacc[0][jt] = __builtin_amdgcn_mfma_f32_16x16x32_bf16(ak[jt][kc], qf[0][kc], sacc[0][jt], 0, 0, 0);
                sacc[1][jt] = __builtin_amdgcn_mfma_f32_16x16x32_bf16(ak[jt][kc], qf[1][kc], sacc[1][jt], 0, 0, 0);
            }
        __builtin_amdgcn_s_setprio(0);

        // ---- softmax (base-2): shuffle-free common path (defer-max)
#pragma unroll
        for (int qt = 0; qt < 2; ++qt) {
            float tl = sacc[qt][0][0];
#pragma unroll
            for (int jt = 0; jt < 2; ++jt)
#pragma unroll
                for (int r = 0; r < 4; ++r) tl = fmaxf(tl, sacc[qt][jt][r]);

            if (__any(tl > mrun[qt] + RESCALE_THR2)) {
                float tmax = fmaxf(tl, __shfl_xor(tl, 16));
                tmax = fmaxf(tmax, __shfl_xor(tmax, 32));
                float mold = mrun[qt];
                float mnew = fmaxf(mold, tmax);
                float scale = exp2_fast(mold - mnew);
                lrun[qt] *= scale;
                mrun[qt] = mnew;
#pragma unroll
                for (int r = 0; r < 4; ++r) {
                    float sc_r = __shfl(scale, lg * 4 + r);
#pragma unroll
                    for (int ct = 0; ct < 8; ++ct) Oacc[qt][ct][r] *= sc_r;
                }
            }
            float m = mrun[qt];
            float psum = 0.f;
#pragma unroll
            for (int jt = 0; jt < 2; ++jt) {
                float p0 = exp2_fast(sacc[qt][jt][0] - m);
                float p1 = exp2_fast(sacc[qt][jt][1] - m);
                float p2 = exp2_fast(sacc[qt][jt][2] - m);
                float p3 = exp2_fast(sacc[qt][jt][3] - m);
                psum += (p0 + p1) + (p2 + p3);
                u32 lo = cvt_pk_bf16(p0, p1);
                u32 hi = cvt_pk_bf16(p2, p3);
                u64 pk = (u64)lo | ((u64)hi << 32);
                *(u64a*)&Ps[w][qt * 16 + li][jt * 16 + lg * 4] = pk;
            }
            lrun[qt] += psum;
        }

        // order P stores before PV reads
        asm volatile("" ::: "memory");

        // ---- PV: O^T[i][c] += P[i][j] * V^T[j][c]  (K=32, one slice)
        bf16x8 ap0 = *(const bf16x8a*)&Ps[w][li][lg * 8];
        bf16x8 ap1 = *(const bf16x8a*)&Ps[w][16 + li][lg * 8];
        __builtin_amdgcn_s_setprio(1);
#pragma unroll
        for (int ct = 0; ct < 8; ++ct) {
            bf16x8 bv = *(const bf16x8a*)&Vs[ct * 16 + li][lg * 8];
            Oacc[0][ct] = __builtin_amdgcn_mfma_f32_16x16x32_bf16(ap0, bv, Oacc[0][ct], 0, 0, 0);
            Oacc[1][ct] = __builtin_amdgcn_mfma_f32_16x16x32_bf16(ap1, bv, Oacc[1][ct], 0, 0, 0);
        }
        __builtin_amdgcn_s_setprio(0);
    }

    // ---- epilogue: finish l (cross-lane reduce), write m/l + bf16 O partial
#pragma unroll
    for (int qt = 0; qt < 2; ++qt) {
        lrun[qt] += __shfl_xor(lrun[qt], 16);
        lrun[qt] += __shfl_xor(lrun[qt], 32);
    }
    const size_t mlbase = ((size_t)kvh * B_DIM + b) * N_TOK + qw;
    if (lg == 0) {
#pragma unroll
        for (int qt = 0; qt < 2; ++qt) {
            Mout[mlbase + qt * 16 + li] = mrun[qt];
            Lout[mlbase + qt * 16 + li] = lrun[qt];
        }
    }
    u16* Ob = Opart + mlbase * CI_DIM;
#pragma unroll
    for (int qt = 0; qt < 2; ++qt)
#pragma unroll
        for (int ct = 0; ct < 8; ++ct)
#pragma unroll
            for (int r = 0; r < 4; ++r)
                Ob[(size_t)(qt * 16 + lg * 4 + r) * CI_DIM + ct * 16 + li] =
                    f2bf(Oacc[qt][ct][r]);
}

// ---------------------------------------------------------------------------
// Kernel C: merge the 4 KV-quarter partials -> attnoB bf16 [B][N][CI]
// (m-deltas are base-2 -> exp2_fast)
// ---------------------------------------------------------------------------
__global__ __launch_bounds__(256) void attn_merge_kernel(
    const u16* __restrict__ Opart, const float* __restrict__ Mout,
    const float* __restrict__ Lout, u16* __restrict__ attnoB)
{
    const int qb = blockIdx.x;
    const int b  = blockIdx.y;
    const int t  = threadIdx.x;
    const int i  = qb * 64 + (t & 63);
    const int c0 = (t >> 6) * 32;

    size_t ns[KVSPLIT];
    float cs[KVSPLIT];
    float m = -1e30f;
#pragma unroll
    for (int s = 0; s < KVSPLIT; ++s) {
        ns[s] = ((size_t)s * B_DIM + b) * N_TOK + i;
        cs[s] = Mout[ns[s]];
        m = fmaxf(m, cs[s]);
    }
    float den = 0.f;
#pragma unroll
    for (int s = 0; s < KVSPLIT; ++s) {
        cs[s] = exp2_fast(cs[s] - m);
        den += Lout[ns[s]] * cs[s];
    }
    float inv = 1.f / den;
#pragma unroll
    for (int s = 0; s < KVSPLIT; ++s) cs[s] *= inv;

    u16* ab = attnoB + ((size_t)b * N_TOK + i) * CI_DIM;
#pragma unroll
    for (int g = 0; g < 4; ++g) {
        float acc[8];
#pragma unroll
        for (int e = 0; e < 8; ++e) acc[e] = 0.f;
#pragma unroll
        for (int s = 0; s < KVSPLIT; ++s) {
            u16x8 ov = *(const u16x8*)&Opart[ns[s] * CI_DIM + c0 + g * 8];
#pragma unroll
            for (int e = 0; e < 8; ++e) acc[e] += bf2f(ov[e]) * cs[s];
        }
        u16x8 res;
#pragma unroll
        for (int e = 0; e < 8; ++e) res[e] = f2bf(acc[e]);
        *(u16x8*)&ab[c0 + g * 8] = res;
    }
}

// ---------------------------------------------------------------------------
// Kernel D: output projection via MFMA + bias + residual, fp32 out.
// (plain global B reads — kernel is HBM-bound (~68MB); r15/r18 both proved
// LDS staging of B only adds overhead here.)
// ---------------------------------------------------------------------------
__global__ __launch_bounds__(256) void out_gemm_kernel(
    const u16* __restrict__ attnoB,  // [B][N][CI] bf16
    const u16* __restrict__ woB,     // [C][CI] bf16
    const float* __restrict__ bo,    // [C]
    const float* __restrict__ x,     // [B][C][N]
    float* __restrict__ out)         // [B][C][N]
{
    const int n0 = blockIdx.x * 64;
    const int b  = blockIdx.y;
    const int t  = threadIdx.x;
    const int w  = t >> 6;
    const int l  = t & 63;
    const int lg = l >> 4;
    const int li = l & 15;
    const int co0 = w * 128;

    const u16* ab = attnoB + (size_t)b * N_TOK * CI_DIM;

    f32x4 acc[8][4];
#pragma unroll
    for (int m = 0; m < 8; ++m)
#pragma unroll
        for (int j = 0; j < 4; ++j)
#pragma unroll
            for (int r = 0; r < 4; ++r) acc[m][j][r] = 0.f;

    const u16* Abase = woB + (size_t)(co0 + li) * CI_DIM + lg * 8;
    const u16* Bbase = ab + (size_t)(n0 + li) * CI_DIM + lg * 8;

#pragma unroll
    for (int kk = 0; kk < 4; ++kk) {
        bf16x8 af[8], bfv[4];
#pragma unroll
        for (int m = 0; m < 8; ++m)
            af[m] = *(const bf16x8*)&Abase[(size_t)(m * 16) * CI_DIM + kk * 32];
#pragma unroll
        for (int j = 0; j < 4; ++j)
            bfv[j] = *(const bf16x8*)&Bbase[(size_t)(j * 16) * CI_DIM + kk * 32];
#pragma unroll
        for (int m = 0; m < 8; ++m)
#pragma unroll
            for (int j = 0; j < 4; ++j)
                acc[m][j] = __builtin_amdgcn_mfma_f32_16x16x32_bf16(
                    af[m], bfv[j], acc[m][j], 0, 0, 0);
    }

    const size_t base = (size_t)b * C_DIM * N_TOK;
#pragma unroll
    for (int m = 0; m < 8; ++m)
#pragma unroll
        for (int r = 0; r < 4; ++r) {
            int co = co0 + m * 16 + lg * 4 + r;
            float bia = bo[co];
#pragma unroll
            for (int j = 0; j < 4; ++j) {
                size_t idx = base + (size_t)co * N_TOK + n0 + j * 16 + li;
                out[idx] = acc[m][j][r] + bia + x[idx];
            }
        }
}

extern "C" void kernel_launch(void* const* d_in, const int* in_sizes, int n_in,
                              void* d_out, int out_size, void* d_ws, size_t ws_size,
                              hipStream_t stream) {
    const float* x  = (const float*)d_in[0];
    const float* wq = (const float*)d_in[1];
    const float* bq = (const float*)d_in[2];
    const float* wk = (const float*)d_in[3];
    const float* bk = (const float*)d_in[4];
    const float* wv = (const float*)d_in[5];
    const float* bv = (const float*)d_in[6];
    const float* wo = (const float*)d_in[7];
    const float* bo = (const float*)d_in[8];
    float* out = (float*)d_out;

    // workspace layout (bytes):
    //  [0,16M)         xT bf16 [B][N][C]  -- dead after qkv_gemm; reused as
    //                  Opart bf16 [4][B][N][CI] (exactly 16 MB)
    //  [16M,16.5M)     wqB/wkB/wvB/woB bf16 (128K each)
    //  [16.5M,20.5M)   qT bf16 [B][N][CI]
    //  [20.5M,24.5M)   kT bf16 [B][N][CI]
    //  [24.5M,28.5M)   vB bf16 [B][CI][N]
    //  [28.5M,+512K)   Mout/Lout f32 [4][B][N] (256K each)
    //  [29M,33M)       attnoB bf16 [B][N][CI]
    char* ws = (char*)d_ws;
    const size_t MB = 1024 * 1024;
    u16*   xT    = (u16*)(ws);
    u16*   Opart = (u16*)(ws);                   // aliases xT (16 MB, exact)
    u16*   wqB   = (u16*)(ws + 16 * MB);
    u16*   wkB   = (u16*)(ws + 16 * MB + 128 * 1024);
    u16*   wvB   = (u16*)(ws + 16 * MB + 256 * 1024);
    u16*   woB   = (u16*)(ws + 16 * MB + 384 * 1024);
    u16*   qT    = (u16*)(ws + 16 * MB + 512 * 1024);
    u16*   kT    = (u16*)(ws + 20 * MB + 512 * 1024);
    u16*   vB    = (u16*)(ws + 24 * MB + 512 * 1024);
    float* Mout  = (float*)(ws + 28 * MB + 512 * 1024);
    float* Lout  = (float*)(ws + 28 * MB + 768 * 1024);
    u16*  attnoB = (u16*)(ws + 29 * MB);

    xpose_kernel<<<dim3(64, 8, 4), 256, 0, stream>>>(x, xT);
    wconv_kernel<<<dim3(32, 4), 256, 0, stream>>>(
        wq, wk, wv, wo, wqB, wkB, wvB, woB);
    qkv_gemm_kernel<<<dim3(32, 4, 3), 256, 0, stream>>>(
        xT, wqB, wkB, wvB, bq, bk, bv, qT, kT, vB);
    attn_mfma_kernel<<<dim3(512), 256, 0, stream>>>(
        qT, kT, vB, Opart, Mout, Lout);
    attn_merge_kernel<<<dim3(64, 4), 256, 0, stream>>>(
        Opart, Mout, Lout, attnoB);
    out_gemm_kernel<<<dim3(64, 4), 256, 0, stream>>>(
        attnoB, woB, bo, x, out);
}